// Round 1
// baseline (322.746 us; speedup 1.0000x reference)
//
#include <hip/hip_runtime.h>
#include <hip/hip_bf16.h>
#include <math.h>

#define B_SZ 4096
#define D_SZ 256
#define THRESH   0.5f
#define MARGIN   0.1f
#define SCALE_POS 2.0f
#define SCALE_NEG 40.0f

// monotonic float->uint mapping for integer atomic min/max
__device__ __forceinline__ unsigned fmap(float f) {
    unsigned u = __float_as_uint(f);
    return (u & 0x80000000u) ? ~u : (u | 0x80000000u);
}
__device__ __forceinline__ float funmap(unsigned u) {
    return (u & 0x80000000u) ? __uint_as_float(u ^ 0x80000000u)
                             : __uint_as_float(~u);
}
#define MINPOS_INIT 0xFF800000u  // fmap(+inf)
#define MAXNEG_INIT 0x007FFFFFu  // fmap(-inf)

// one block (1 wave) per row: rsqrt of row sumsq + init scratch arrays
__global__ void norm_init_kernel(const float* __restrict__ feats,
                                 float* __restrict__ rn,
                                 unsigned* __restrict__ minpos,
                                 unsigned* __restrict__ maxneg,
                                 float* __restrict__ possum,
                                 float* __restrict__ negsum) {
    int row = blockIdx.x;
    int lane = threadIdx.x;             // 64 lanes
    const float4 v = *(const float4*)(feats + (size_t)row * D_SZ + lane * 4);
    float s = v.x * v.x + v.y * v.y + v.z * v.z + v.w * v.w;
#pragma unroll
    for (int m = 32; m; m >>= 1) s += __shfl_xor(s, m);
    if (lane == 0) {
        rn[row] = 1.0f / sqrtf(s);
        minpos[row] = MINPOS_INIT;
        maxneg[row] = MAXNEG_INIT;
        possum[row] = 0.f;
        negsum[row] = 0.f;
    }
}

// PHASE 0: per-row min(sim over positives), max(sim over negatives)
// PHASE 1: masked exp-sums using min/max from phase 0
template <int PHASE>
__global__ __launch_bounds__(256) void sim_pass(
    const float* __restrict__ feats, const float* __restrict__ rn,
    const int* __restrict__ labels, const float* __restrict__ simw,
    unsigned* __restrict__ minpos, unsigned* __restrict__ maxneg,
    float* __restrict__ possum, float* __restrict__ negsum) {
    // [k][row] layout, stride 68 floats: keeps float4 reads 16B-aligned,
    // staging writes spread over 8 banks, frag reads broadcast/2-way.
    __shared__ float lA[64][68];
    __shared__ float lB[64][68];
    const int tx = threadIdx.x, ty = threadIdx.y;
    const int t = ty * 16 + tx;
    const int bi = blockIdx.y, bj = blockIdx.x;
    const int i0 = bi * 64, j0 = bj * 64;

    float acc[4][4] = {};

    for (int kc = 0; kc < D_SZ; kc += 64) {
        __syncthreads();
#pragma unroll
        for (int l = 0; l < 4; ++l) {
            int p = t + l * 256;          // 1024 float4 slots per tile
            int row = p >> 4, kq = p & 15;
            float4 va = *(const float4*)(feats + (size_t)(i0 + row) * D_SZ + kc + kq * 4);
            float4 vb = *(const float4*)(feats + (size_t)(j0 + row) * D_SZ + kc + kq * 4);
            lA[kq * 4 + 0][row] = va.x; lA[kq * 4 + 1][row] = va.y;
            lA[kq * 4 + 2][row] = va.z; lA[kq * 4 + 3][row] = va.w;
            lB[kq * 4 + 0][row] = vb.x; lB[kq * 4 + 1][row] = vb.y;
            lB[kq * 4 + 2][row] = vb.z; lB[kq * 4 + 3][row] = vb.w;
        }
        __syncthreads();
#pragma unroll 16
        for (int k = 0; k < 64; ++k) {
            float4 av = *(const float4*)&lA[k][ty * 4];
            float4 bv = *(const float4*)&lB[k][tx * 4];
            float a[4] = {av.x, av.y, av.z, av.w};
            float b[4] = {bv.x, bv.y, bv.z, bv.w};
#pragma unroll
            for (int r = 0; r < 4; ++r)
#pragma unroll
                for (int c = 0; c < 4; ++c)
                    acc[r][c] = fmaf(a[r], b[c], acc[r][c]);
        }
    }

    int iL[4], jL[4];
    float ri[4], rj[4];
#pragma unroll
    for (int r = 0; r < 4; ++r) { iL[r] = labels[i0 + ty * 4 + r]; ri[r] = rn[i0 + ty * 4 + r]; }
#pragma unroll
    for (int c = 0; c < 4; ++c) { jL[c] = labels[j0 + tx * 4 + c]; rj[c] = rn[j0 + tx * 4 + c]; }

    if (PHASE == 0) {
#pragma unroll
        for (int r = 0; r < 4; ++r) {
            float mn = INFINITY, mx = -INFINITY;
#pragma unroll
            for (int c = 0; c < 4; ++c) {
                float s = acc[r][c] * ri[r] * rj[c];
                if (iL[r] == jL[c]) mn = fminf(mn, s);
                else                mx = fmaxf(mx, s);
            }
#pragma unroll
            for (int m = 1; m < 16; m <<= 1) {   // 16 lanes share a row
                mn = fminf(mn, __shfl_xor(mn, m));
                mx = fmaxf(mx, __shfl_xor(mx, m));
            }
            if (tx == 0) {
                int i = i0 + ty * 4 + r;
                if (mn != INFINITY)  atomicMin(&minpos[i], fmap(mn));
                if (mx != -INFINITY) atomicMax(&maxneg[i], fmap(mx));
            }
        }
    } else {
#pragma unroll
        for (int r = 0; r < 4; ++r) {
            int i = i0 + ty * 4 + r;
            unsigned mpu = minpos[i], mnu = maxneg[i];
            float minp = funmap(mpu);
            bool hasneg = (mnu != MAXNEG_INIT);
            float maxn = funmap(mnu);
            const float4 wv = *(const float4*)(simw + (size_t)i * B_SZ + j0 + tx * 4);
            float wa[4] = {wv.x, wv.y, wv.z, wv.w};
            float ps = 0.f, ns = 0.f;
#pragma unroll
            for (int c = 0; c < 4; ++c) {
                float s = acc[r][c] * ri[r] * rj[c];
                float w = wa[c];
                if (iL[r] == jL[c]) {
                    if (!hasneg || (s - MARGIN < maxn))
                        ps += expf(-SCALE_POS * (s - THRESH) + w);
                } else {
                    if (s + MARGIN > minp)
                        ns += expf(SCALE_NEG * (s - THRESH) - w);
                }
            }
#pragma unroll
            for (int m = 1; m < 16; m <<= 1) {
                ps += __shfl_xor(ps, m);
                ns += __shfl_xor(ns, m);
            }
            if (tx == 0) {
                if (ps != 0.f) atomicAdd(&possum[i], ps);
                if (ns != 0.f) atomicAdd(&negsum[i], ns);
            }
        }
    }
}

__global__ void final_kernel(const float* __restrict__ possum,
                             const float* __restrict__ negsum,
                             float* __restrict__ out) {
    __shared__ float red[256];
    int t = threadIdx.x;
    float acc = 0.f;
    for (int i = t; i < B_SZ; i += 256)
        acc += log1pf(possum[i]) * (1.0f / SCALE_POS) +
               log1pf(negsum[i]) * (1.0f / SCALE_NEG);
    red[t] = acc;
    __syncthreads();
    for (int s = 128; s > 0; s >>= 1) {
        if (t < s) red[t] += red[t + s];
        __syncthreads();
    }
    if (t == 0) out[0] = red[0] / (float)B_SZ;
}

extern "C" void kernel_launch(void* const* d_in, const int* in_sizes, int n_in,
                              void* d_out, int out_size, void* d_ws, size_t ws_size,
                              hipStream_t stream) {
    const float* feats  = (const float*)d_in[0];
    const float* simw   = (const float*)d_in[1];
    const int*   labels = (const int*)d_in[2];
    float* out = (float*)d_out;

    char* ws = (char*)d_ws;                      // 80 KB total scratch
    float*    rn     = (float*)ws;
    unsigned* minpos = (unsigned*)(ws + 1 * B_SZ * 4);
    unsigned* maxneg = (unsigned*)(ws + 2 * B_SZ * 4);
    float*    possum = (float*)(ws + 3 * B_SZ * 4);
    float*    negsum = (float*)(ws + 4 * B_SZ * 4);

    norm_init_kernel<<<B_SZ, 64, 0, stream>>>(feats, rn, minpos, maxneg, possum, negsum);

    dim3 grid(B_SZ / 64, B_SZ / 64), block(16, 16);
    sim_pass<0><<<grid, block, 0, stream>>>(feats, rn, labels, simw, minpos, maxneg, possum, negsum);
    sim_pass<1><<<grid, block, 0, stream>>>(feats, rn, labels, simw, minpos, maxneg, possum, negsum);

    final_kernel<<<1, 256, 0, stream>>>(possum, negsum, out);
}

// Round 2
// 166.679 us; speedup vs baseline: 1.9363x; 1.9363x over previous
//
#include <hip/hip_runtime.h>
#include <hip/hip_bf16.h>
#include <math.h>

#define B_SZ 4096
#define D_SZ 256
#define MARGIN   0.1f

typedef __attribute__((ext_vector_type(8))) __bf16 bf16x8;
typedef __attribute__((ext_vector_type(4))) float f32x4;

// monotonic float->uint mapping for integer atomic min/max
__device__ __forceinline__ unsigned fmap(float f) {
    unsigned u = __float_as_uint(f);
    return (u & 0x80000000u) ? ~u : (u | 0x80000000u);
}
__device__ __forceinline__ float funmap(unsigned u) {
    return (u & 0x80000000u) ? __uint_as_float(u ^ 0x80000000u)
                             : __uint_as_float(~u);
}
#define MINPOS_INIT 0xFF800000u  // fmap(+inf)
#define MAXNEG_INIT 0x007FFFFFu  // fmap(-inf)

__device__ __forceinline__ unsigned short f2bf(float f) {
    unsigned u = __float_as_uint(f);
    unsigned r = (u + 0x7FFFu + ((u >> 16) & 1u)) >> 16;   // RNE
    return (unsigned short)r;
}

// one wave per row: rsqrt(sumsq), write normalized bf16 feats, init scratch
__global__ void norm_init_kernel(const float* __restrict__ feats,
                                 unsigned short* __restrict__ fb,
                                 unsigned* __restrict__ minpos,
                                 unsigned* __restrict__ maxneg,
                                 float* __restrict__ possum,
                                 float* __restrict__ negsum) {
    int row = blockIdx.x;
    int lane = threadIdx.x;             // 64 lanes
    const float4 v = *(const float4*)(feats + (size_t)row * D_SZ + lane * 4);
    float s = v.x * v.x + v.y * v.y + v.z * v.z + v.w * v.w;
#pragma unroll
    for (int m = 32; m; m >>= 1) s += __shfl_xor(s, m);
    float rinv = 1.0f / sqrtf(s);
    short4 st;
    st.x = (short)f2bf(v.x * rinv);
    st.y = (short)f2bf(v.y * rinv);
    st.z = (short)f2bf(v.z * rinv);
    st.w = (short)f2bf(v.w * rinv);
    *(short4*)(fb + (size_t)row * D_SZ + lane * 4) = st;
    if (lane == 0) {
        minpos[row] = MINPOS_INIT;
        maxneg[row] = MAXNEG_INIT;
        possum[row] = 0.f;
        negsum[row] = 0.f;
    }
}

// 128x128 tile per block, 4 waves each owning a 64x64 quadrant.
// Fragments loaded straight from global (fb is 2 MB -> L2/L3 resident).
// PHASE 0: per-row min(pos sim) / max(neg sim).  PHASE 1: masked exp-sums.
template <int PHASE>
__global__ __launch_bounds__(256) void sim_pass(
    const unsigned short* __restrict__ fb,
    const int* __restrict__ labels,
    const float* __restrict__ simw,
    unsigned* __restrict__ minpos, unsigned* __restrict__ maxneg,
    float* __restrict__ possum, float* __restrict__ negsum) {
    const int t = threadIdx.x;
    const int lane = t & 63, w = t >> 6;
    const int i0 = blockIdx.y * 128 + (w >> 1) * 64;
    const int j0 = blockIdx.x * 128 + (w & 1) * 64;

    const int fr = lane & 15;        // frag row (A) / col (B)
    const int kg = lane >> 4;        // k-group: elems kg*8 .. kg*8+7

    const unsigned short* Ab = fb + (size_t)(i0 + fr) * D_SZ + kg * 8;
    const unsigned short* Bb = fb + (size_t)(j0 + fr) * D_SZ + kg * 8;

    f32x4 acc[4][4];
#pragma unroll
    for (int m = 0; m < 4; ++m)
#pragma unroll
        for (int n = 0; n < 4; ++n)
            acc[m][n] = (f32x4){0.f, 0.f, 0.f, 0.f};

#pragma unroll 2
    for (int kk = 0; kk < 8; ++kk) {
        bf16x8 a[4], b[4];
#pragma unroll
        for (int m = 0; m < 4; ++m)
            a[m] = *reinterpret_cast<const bf16x8*>(Ab + (size_t)m * 16 * D_SZ + kk * 32);
#pragma unroll
        for (int n = 0; n < 4; ++n)
            b[n] = *reinterpret_cast<const bf16x8*>(Bb + (size_t)n * 16 * D_SZ + kk * 32);
#pragma unroll
        for (int m = 0; m < 4; ++m)
#pragma unroll
            for (int n = 0; n < 4; ++n)
                acc[m][n] = __builtin_amdgcn_mfma_f32_16x16x32_bf16(a[m], b[n], acc[m][n], 0, 0, 0);
    }

    // C/D mapping (m89-verified): col = lane&15, row = (lane>>4)*4 + reg
    int jLab[4];
#pragma unroll
    for (int n = 0; n < 4; ++n) jLab[n] = labels[j0 + n * 16 + fr];

#pragma unroll
    for (int m = 0; m < 4; ++m) {
#pragma unroll
        for (int r = 0; r < 4; ++r) {
            const int i = i0 + m * 16 + kg * 4 + r;
            const int il = labels[i];
            if (PHASE == 0) {
                float mn = INFINITY, mx = -INFINITY;
#pragma unroll
                for (int n = 0; n < 4; ++n) {
                    float s = acc[m][n][r];
                    if (il == jLab[n]) mn = fminf(mn, s);
                    else               mx = fmaxf(mx, s);
                }
#pragma unroll
                for (int msk = 1; msk < 16; msk <<= 1) {
                    mn = fminf(mn, __shfl_xor(mn, msk));
                    mx = fmaxf(mx, __shfl_xor(mx, msk));
                }
                if (fr == 0) {
                    if (mn != INFINITY)  atomicMin(&minpos[i], fmap(mn));
                    if (mx != -INFINITY) atomicMax(&maxneg[i], fmap(mx));
                }
            } else {
                const unsigned mnu = maxneg[i];
                const float minp = funmap(minpos[i]);
                const bool hasneg = (mnu != MAXNEG_INIT);
                const float maxn = funmap(mnu);
                const float* wrow = simw + (size_t)i * B_SZ + j0 + fr;
                float ps = 0.f, ns = 0.f;
#pragma unroll
                for (int n = 0; n < 4; ++n) {
                    float s = acc[m][n][r];
                    float wv = wrow[n * 16];
                    if (il == jLab[n]) {
                        if (!hasneg || (s - MARGIN < maxn))
                            ps += __expf(fmaf(-2.f, s, 1.f) + wv);    // exp(-2(s-.5)+w)
                    } else {
                        if (s + MARGIN > minp)
                            ns += __expf(fmaf(40.f, s, -20.f) - wv);  // exp(40(s-.5)-w)
                    }
                }
#pragma unroll
                for (int msk = 1; msk < 16; msk <<= 1) {
                    ps += __shfl_xor(ps, msk);
                    ns += __shfl_xor(ns, msk);
                }
                if (fr == 0) {
                    if (ps != 0.f) atomicAdd(&possum[i], ps);
                    if (ns != 0.f) atomicAdd(&negsum[i], ns);
                }
            }
        }
    }
}

__global__ void final_kernel(const float* __restrict__ possum,
                             const float* __restrict__ negsum,
                             float* __restrict__ out) {
    __shared__ float red[256];
    int t = threadIdx.x;
    float acc = 0.f;
    for (int i = t; i < B_SZ; i += 256)
        acc += log1pf(possum[i]) * 0.5f +
               log1pf(negsum[i]) * 0.025f;
    red[t] = acc;
    __syncthreads();
    for (int s = 128; s > 0; s >>= 1) {
        if (t < s) red[t] += red[t + s];
        __syncthreads();
    }
    if (t == 0) out[0] = red[0] / (float)B_SZ;
}

extern "C" void kernel_launch(void* const* d_in, const int* in_sizes, int n_in,
                              void* d_out, int out_size, void* d_ws, size_t ws_size,
                              hipStream_t stream) {
    const float* feats  = (const float*)d_in[0];
    const float* simw   = (const float*)d_in[1];
    const int*   labels = (const int*)d_in[2];
    float* out = (float*)d_out;

    char* ws = (char*)d_ws;
    unsigned* minpos = (unsigned*)ws;
    unsigned* maxneg = (unsigned*)(ws + 1 * B_SZ * 4);
    float*    possum = (float*)(ws + 2 * B_SZ * 4);
    float*    negsum = (float*)(ws + 3 * B_SZ * 4);
    unsigned short* fb = (unsigned short*)(ws + 4 * B_SZ * 4);  // 2 MB bf16 feats

    norm_init_kernel<<<B_SZ, 64, 0, stream>>>(feats, fb, minpos, maxneg, possum, negsum);

    dim3 grid(B_SZ / 128, B_SZ / 128), block(256);
    sim_pass<0><<<grid, block, 0, stream>>>(fb, labels, simw, minpos, maxneg, possum, negsum);
    sim_pass<1><<<grid, block, 0, stream>>>(fb, labels, simw, minpos, maxneg, possum, negsum);

    final_kernel<<<1, 256, 0, stream>>>(possum, negsum, out);
}

// Round 3
// 110.918 us; speedup vs baseline: 2.9098x; 1.5027x over previous
//
#include <hip/hip_runtime.h>
#include <hip/hip_bf16.h>
#include <math.h>

#define B_SZ 4096
#define D_SZ 256
#define MARGIN   0.1f

typedef __attribute__((ext_vector_type(8))) __bf16 bf16x8;
typedef __attribute__((ext_vector_type(4))) float f32x4;

// monotonic float->uint mapping for integer atomic min/max
__device__ __forceinline__ unsigned fmap(float f) {
    unsigned u = __float_as_uint(f);
    return (u & 0x80000000u) ? ~u : (u | 0x80000000u);
}
__device__ __forceinline__ float funmap(unsigned u) {
    return (u & 0x80000000u) ? __uint_as_float(u ^ 0x80000000u)
                             : __uint_as_float(~u);
}
#define MINPOS_INIT 0xFF800000u  // fmap(+inf)
#define MAXNEG_INIT 0x007FFFFFu  // fmap(-inf)

__device__ __forceinline__ unsigned short f2bf(float f) {
    unsigned u = __float_as_uint(f);
    unsigned r = (u + 0x7FFFu + ((u >> 16) & 1u)) >> 16;   // RNE
    return (unsigned short)r;
}

__device__ __forceinline__ void gload_lds16(const void* g, void* lds) {
    __builtin_amdgcn_global_load_lds(
        (const __attribute__((address_space(1))) void*)g,
        (__attribute__((address_space(3))) void*)lds, 16, 0, 0);
}

// one wave per row: rsqrt(sumsq), write normalized bf16 feats, init scratch
__global__ void norm_init_kernel(const float* __restrict__ feats,
                                 unsigned short* __restrict__ fb,
                                 unsigned* __restrict__ minpos,
                                 unsigned* __restrict__ maxneg,
                                 float* __restrict__ possum,
                                 float* __restrict__ negsum) {
    int row = blockIdx.x;
    int lane = threadIdx.x;             // 64 lanes
    const float4 v = *(const float4*)(feats + (size_t)row * D_SZ + lane * 4);
    float s = v.x * v.x + v.y * v.y + v.z * v.z + v.w * v.w;
#pragma unroll
    for (int m = 32; m; m >>= 1) s += __shfl_xor(s, m);
    float rinv = 1.0f / sqrtf(s);
    short4 st;
    st.x = (short)f2bf(v.x * rinv);
    st.y = (short)f2bf(v.y * rinv);
    st.z = (short)f2bf(v.z * rinv);
    st.w = (short)f2bf(v.w * rinv);
    *(short4*)(fb + (size_t)row * D_SZ + lane * 4) = st;
    if (lane == 0) {
        minpos[row] = MINPOS_INIT;
        maxneg[row] = MAXNEG_INIT;
        possum[row] = 0.f;
        negsum[row] = 0.f;
    }
}

// 128x128 tile, BK=64, 4 waves each owning a 64x64 quadrant (m97 structure).
// LDS content is XOR-swizzled (16B-chunk col ^ row&7) via pre-swizzled
// global source (linear global_load_lds dest, rule 21); fragment ds_read_b128
// applies the same XOR -> near-minimal 8-lanes-per-16B-slot aliasing.
// PHASE 0: per-row min(pos sim) / max(neg sim).  PHASE 1: masked exp-sums.
template <int PHASE>
__global__ __launch_bounds__(256) void sim_pass(
    const unsigned short* __restrict__ fb,
    const int* __restrict__ labels,
    const float* __restrict__ simw,
    unsigned* __restrict__ minpos, unsigned* __restrict__ maxneg,
    float* __restrict__ possum, float* __restrict__ negsum) {
    __shared__ unsigned short lA[128 * 64];
    __shared__ unsigned short lB[128 * 64];
    const int t = threadIdx.x;
    const int lane = t & 63, w = t >> 6;
    const int wr = w >> 1, wc = w & 1;
    const int i0 = blockIdx.y * 128, j0 = blockIdx.x * 128;
    const int fr = lane & 15, kg = lane >> 4;

    // staging source mapping: lane writes LDS (row=lane>>3, col16=lane&7);
    // source col16 = (lane&7) ^ (row&7)  (involution within 8-row stripe)
    const int srow = lane >> 3;
    const int scol = ((lane & 7) ^ srow) * 8;      // element offset

    f32x4 acc[4][4];
#pragma unroll
    for (int m = 0; m < 4; ++m)
#pragma unroll
        for (int n = 0; n < 4; ++n)
            acc[m][n] = (f32x4){0.f, 0.f, 0.f, 0.f};

    const char* pA = (const char*)lA + (wr * 64 + fr) * 128;
    const char* pB = (const char*)lB + (wc * 64 + fr) * 128;
    const int q = (kg * 16) ^ ((fr & 7) << 4);     // swizzled k-chunk offset

    for (int kc = 0; kc < D_SZ; kc += 64) {
        __syncthreads();
#pragma unroll
        for (int inst = 0; inst < 4; ++inst) {
            const int r8 = w * 32 + inst * 8;
            gload_lds16(fb + (size_t)(i0 + r8 + srow) * D_SZ + kc + scol, lA + r8 * 64);
            gload_lds16(fb + (size_t)(j0 + r8 + srow) * D_SZ + kc + scol, lB + r8 * 64);
        }
        asm volatile("s_waitcnt vmcnt(0)" ::: "memory");
        __syncthreads();
#pragma unroll
        for (int kk = 0; kk < 2; ++kk) {
            const int off = q ^ (kk * 64);
            bf16x8 a[4], b[4];
#pragma unroll
            for (int m = 0; m < 4; ++m)
                a[m] = *(const bf16x8*)(pA + m * 2048 + off);
#pragma unroll
            for (int n = 0; n < 4; ++n)
                b[n] = *(const bf16x8*)(pB + n * 2048 + off);
#pragma unroll
            for (int m = 0; m < 4; ++m)
#pragma unroll
                for (int n = 0; n < 4; ++n)
                    acc[m][n] = __builtin_amdgcn_mfma_f32_16x16x32_bf16(a[m], b[n], acc[m][n], 0, 0, 0);
        }
    }

    // C/D mapping (m89-verified): col = lane&15, row = (lane>>4)*4 + reg
    const int iBase = i0 + wr * 64, jBase = j0 + wc * 64;
    int jLab[4];
#pragma unroll
    for (int n = 0; n < 4; ++n) jLab[n] = labels[jBase + n * 16 + fr];

#pragma unroll
    for (int m = 0; m < 4; ++m) {
#pragma unroll
        for (int r = 0; r < 4; ++r) {
            const int i = iBase + m * 16 + kg * 4 + r;
            const int il = labels[i];
            if (PHASE == 0) {
                float mn = INFINITY, mx = -INFINITY;
#pragma unroll
                for (int n = 0; n < 4; ++n) {
                    float s = acc[m][n][r];
                    if (il == jLab[n]) mn = fminf(mn, s);
                    else               mx = fmaxf(mx, s);
                }
#pragma unroll
                for (int msk = 1; msk < 16; msk <<= 1) {
                    mn = fminf(mn, __shfl_xor(mn, msk));
                    mx = fmaxf(mx, __shfl_xor(mx, msk));
                }
                if (fr == 0) {
                    if (mn != INFINITY)  atomicMin(&minpos[i], fmap(mn));
                    if (mx != -INFINITY) atomicMax(&maxneg[i], fmap(mx));
                }
            } else {
                const unsigned mnu = maxneg[i];
                const float minp = funmap(minpos[i]);
                const bool hasneg = (mnu != MAXNEG_INIT);
                const float maxn = funmap(mnu);
                const float* wrow = simw + (size_t)i * B_SZ + jBase + fr;
                float ps = 0.f, ns = 0.f;
#pragma unroll
                for (int n = 0; n < 4; ++n) {
                    float s = acc[m][n][r];
                    float wv = wrow[n * 16];
                    if (il == jLab[n]) {
                        if (!hasneg || (s - MARGIN < maxn))
                            ps += __expf(fmaf(-2.f, s, 1.f) + wv);    // exp(-2(s-.5)+w)
                    } else {
                        if (s + MARGIN > minp)
                            ns += __expf(fmaf(40.f, s, -20.f) - wv);  // exp(40(s-.5)-w)
                    }
                }
#pragma unroll
                for (int msk = 1; msk < 16; msk <<= 1) {
                    ps += __shfl_xor(ps, msk);
                    ns += __shfl_xor(ns, msk);
                }
                if (fr == 0) {
                    if (ps != 0.f) atomicAdd(&possum[i], ps);
                    if (ns != 0.f) atomicAdd(&negsum[i], ns);
                }
            }
        }
    }
}

__global__ void final_kernel(const float* __restrict__ possum,
                             const float* __restrict__ negsum,
                             float* __restrict__ out) {
    __shared__ float red[256];
    int t = threadIdx.x;
    float acc = 0.f;
    for (int i = t; i < B_SZ; i += 256)
        acc += log1pf(possum[i]) * 0.5f +
               log1pf(negsum[i]) * 0.025f;
    red[t] = acc;
    __syncthreads();
    for (int s = 128; s > 0; s >>= 1) {
        if (t < s) red[t] += red[t + s];
        __syncthreads();
    }
    if (t == 0) out[0] = red[0] / (float)B_SZ;
}

extern "C" void kernel_launch(void* const* d_in, const int* in_sizes, int n_in,
                              void* d_out, int out_size, void* d_ws, size_t ws_size,
                              hipStream_t stream) {
    const float* feats  = (const float*)d_in[0];
    const float* simw   = (const float*)d_in[1];
    const int*   labels = (const int*)d_in[2];
    float* out = (float*)d_out;

    char* ws = (char*)d_ws;
    unsigned* minpos = (unsigned*)ws;
    unsigned* maxneg = (unsigned*)(ws + 1 * B_SZ * 4);
    float*    possum = (float*)(ws + 2 * B_SZ * 4);
    float*    negsum = (float*)(ws + 3 * B_SZ * 4);
    unsigned short* fb = (unsigned short*)(ws + 4 * B_SZ * 4);  // 2 MB bf16 feats

    norm_init_kernel<<<B_SZ, 64, 0, stream>>>(feats, fb, minpos, maxneg, possum, negsum);

    dim3 grid(B_SZ / 128, B_SZ / 128), block(256);
    sim_pass<0><<<grid, block, 0, stream>>>(fb, labels, simw, minpos, maxneg, possum, negsum);
    sim_pass<1><<<grid, block, 0, stream>>>(fb, labels, simw, minpos, maxneg, possum, negsum);

    final_kernel<<<1, 256, 0, stream>>>(possum, negsum, out);
}

// Round 4
// 52.284 us; speedup vs baseline: 6.1730x; 2.1215x over previous
//
#include <hip/hip_runtime.h>
#include <hip/hip_bf16.h>
#include <math.h>

#define B_SZ 4096
#define D_SZ 256
#define MARGIN   0.1f

typedef __attribute__((ext_vector_type(8))) __bf16 bf16x8;
typedef __attribute__((ext_vector_type(4))) float f32x4;
typedef __attribute__((ext_vector_type(8))) unsigned short u16x8;

// monotonic float->uint mapping for integer atomic min/max (fallback path)
__device__ __forceinline__ unsigned fmap(float f) {
    unsigned u = __float_as_uint(f);
    return (u & 0x80000000u) ? ~u : (u | 0x80000000u);
}
__device__ __forceinline__ float funmap(unsigned u) {
    return (u & 0x80000000u) ? __uint_as_float(u ^ 0x80000000u)
                             : __uint_as_float(~u);
}
#define MINPOS_INIT 0xFF800000u
#define MAXNEG_INIT 0x007FFFFFu

__device__ __forceinline__ unsigned short f2bf(float f) {
    unsigned u = __float_as_uint(f);
    unsigned r = (u + 0x7FFFu + ((u >> 16) & 1u)) >> 16;   // RNE
    return (unsigned short)r;
}

__device__ __forceinline__ void gload_lds16(const void* g, void* lds) {
    __builtin_amdgcn_global_load_lds(
        (const __attribute__((address_space(1))) void*)g,
        (__attribute__((address_space(3))) void*)lds, 16, 0, 0);
}

// one wave per row: rsqrt(sumsq), write normalized bf16 feats, init scratch
__global__ void norm_init_kernel(const float* __restrict__ feats,
                                 unsigned short* __restrict__ fb,
                                 unsigned* __restrict__ minpos,
                                 unsigned* __restrict__ maxneg,
                                 float* __restrict__ possum,
                                 float* __restrict__ negsum) {
    int row = blockIdx.x;
    int lane = threadIdx.x;
    const float4 v = *(const float4*)(feats + (size_t)row * D_SZ + lane * 4);
    float s = v.x * v.x + v.y * v.y + v.z * v.z + v.w * v.w;
#pragma unroll
    for (int m = 32; m; m >>= 1) s += __shfl_xor(s, m);
    float rinv = 1.0f / sqrtf(s);
    short4 st;
    st.x = (short)f2bf(v.x * rinv);
    st.y = (short)f2bf(v.y * rinv);
    st.z = (short)f2bf(v.z * rinv);
    st.w = (short)f2bf(v.w * rinv);
    *(short4*)(fb + (size_t)row * D_SZ + lane * 4) = st;
    if (lane == 0) {
        minpos[row] = MINPOS_INIT;
        maxneg[row] = MAXNEG_INIT;
        possum[row] = 0.f;
        negsum[row] = 0.f;
    }
}

// ================= BIG-WS PATH =================
// 128x128 tile, BK=32 double-buffered prefetch. LDS rows are 64 B; the 16B
// chunk index is XOR-swizzled by row bits so quarter-wave b128 reads are
// 2-way (free). Staging keeps LDS linear and pre-swizzles the global source
// chunk (rule 21, involution).
__device__ __forceinline__ void gemm_tile(const unsigned short* __restrict__ fb,
                                          unsigned short* lA0, unsigned short* lB0,
                                          int i0, int j0, int t, f32x4 acc[4][4]) {
    const int lane = t & 63, w = t >> 6;
    const int wr = w >> 1, wc = w & 1;
    const int fr = lane & 15, kg = lane >> 4;
    const int srow = lane >> 2, schunk = lane & 3;

#pragma unroll
    for (int m = 0; m < 4; ++m)
#pragma unroll
        for (int n = 0; n < 4; ++n) acc[m][n] = (f32x4){0.f, 0.f, 0.f, 0.f};

    auto stage = [&](int buf, int kc) {
#pragma unroll
        for (int half = 0; half < 2; ++half) {
            const int R0 = w * 32 + half * 16;       // 16 rows per instruction
            const int row = R0 + srow;
            const int off = ((schunk ^ ((row >> 1) & 3)) << 3);
            gload_lds16(fb + (size_t)(i0 + row) * D_SZ + kc + off,
                        lA0 + buf * (128 * 32) + R0 * 32);
            gload_lds16(fb + (size_t)(j0 + row) * D_SZ + kc + off,
                        lB0 + buf * (128 * 32) + R0 * 32);
        }
    };

    stage(0, 0);
    asm volatile("s_waitcnt vmcnt(0)" ::: "memory");
    __syncthreads();

#pragma unroll
    for (int s = 0; s < 8; ++s) {
        const int cur = s & 1;
        if (s < 7) stage(cur ^ 1, (s + 1) * 32);     // prefetch next K-slice
        const unsigned short* A  = lA0 + cur * (128 * 32);
        const unsigned short* Bp = lB0 + cur * (128 * 32);
        bf16x8 a[4], b[4];
#pragma unroll
        for (int m = 0; m < 4; ++m) {
            const int row = wr * 64 + m * 16 + fr;
            a[m] = *(const bf16x8*)(A + row * 32 + ((kg ^ ((row >> 1) & 3)) << 3));
        }
#pragma unroll
        for (int n = 0; n < 4; ++n) {
            const int row = wc * 64 + n * 16 + fr;
            b[n] = *(const bf16x8*)(Bp + row * 32 + ((kg ^ ((row >> 1) & 3)) << 3));
        }
#pragma unroll
        for (int m = 0; m < 4; ++m)
#pragma unroll
            for (int n = 0; n < 4; ++n)
                acc[m][n] = __builtin_amdgcn_mfma_f32_16x16x32_bf16(a[m], b[n], acc[m][n], 0, 0, 0);
        if (s < 7) {
            asm volatile("s_waitcnt vmcnt(0)" ::: "memory");
            __syncthreads();
        }
    }
}

__global__ __launch_bounds__(256, 4) void gemm_store(const unsigned short* __restrict__ fb,
                                                     unsigned short* __restrict__ simb) {
    __shared__ unsigned short lA[2 * 128 * 32];
    __shared__ unsigned short lB[2 * 128 * 32];
    const int t = threadIdx.x;
    const int i0 = blockIdx.y * 128, j0 = blockIdx.x * 128;
    f32x4 acc[4][4];
    gemm_tile(fb, lA, lB, i0, j0, t, acc);
    const int lane = t & 63, w = t >> 6;
    const int wr = w >> 1, wc = w & 1, fr = lane & 15, kg = lane >> 4;
#pragma unroll
    for (int m = 0; m < 4; ++m)
#pragma unroll
        for (int r = 0; r < 4; ++r) {
            const size_t row = i0 + wr * 64 + m * 16 + kg * 4 + r;
#pragma unroll
            for (int n = 0; n < 4; ++n)
                simb[row * B_SZ + j0 + wc * 64 + n * 16 + fr] = f2bf(acc[m][n][r]);
        }
}

// one block per row: stream sim(bf16) + simw + labels, block-local min/max,
// then exp sums from the SAME registers. No atomics -> bit-deterministic.
__global__ __launch_bounds__(256) void row_pass(const unsigned short* __restrict__ simb,
                                                const float* __restrict__ simw,
                                                const int* __restrict__ labels,
                                                float* __restrict__ rowloss) {
    const int i = blockIdx.x, t = threadIdx.x;
    const int lane = t & 63, w = t >> 6;
    const int il = labels[i];
    float sv[16], wv[16];
    int lj[16];
    {
        const u16x8* sp = (const u16x8*)(simb + (size_t)i * B_SZ + t * 16);
        u16x8 s0 = sp[0], s1 = sp[1];
#pragma unroll
        for (int e = 0; e < 8; ++e) {
            sv[e]     = __uint_as_float((unsigned)s0[e] << 16);
            sv[8 + e] = __uint_as_float((unsigned)s1[e] << 16);
        }
        const float4* wp = (const float4*)(simw + (size_t)i * B_SZ + t * 16);
#pragma unroll
        for (int q = 0; q < 4; ++q) {
            float4 wq = wp[q];
            wv[q * 4 + 0] = wq.x; wv[q * 4 + 1] = wq.y;
            wv[q * 4 + 2] = wq.z; wv[q * 4 + 3] = wq.w;
        }
        const int4* lp = (const int4*)(labels + t * 16);
#pragma unroll
        for (int q = 0; q < 4; ++q) {
            int4 lq = lp[q];
            lj[q * 4 + 0] = lq.x; lj[q * 4 + 1] = lq.y;
            lj[q * 4 + 2] = lq.z; lj[q * 4 + 3] = lq.w;
        }
    }
    float mn = INFINITY, mx = -INFINITY;
#pragma unroll
    for (int e = 0; e < 16; ++e) {
        if (lj[e] == il) mn = fminf(mn, sv[e]);
        else             mx = fmaxf(mx, sv[e]);
    }
#pragma unroll
    for (int msk = 1; msk < 64; msk <<= 1) {
        mn = fminf(mn, __shfl_xor(mn, msk));
        mx = fmaxf(mx, __shfl_xor(mx, msk));
    }
    __shared__ float smn[4], smx[4], sps[4], sns[4];
    if (lane == 0) { smn[w] = mn; smx[w] = mx; }
    __syncthreads();
    mn = fminf(fminf(smn[0], smn[1]), fminf(smn[2], smn[3]));
    mx = fmaxf(fmaxf(smx[0], smx[1]), fmaxf(smx[2], smx[3]));
    const bool hasneg = (mx != -INFINITY);
    float ps = 0.f, ns = 0.f;
#pragma unroll
    for (int e = 0; e < 16; ++e) {
        const float s = sv[e];
        if (lj[e] == il) {
            if (!hasneg || (s - MARGIN < mx))
                ps += __expf(fmaf(-2.f, s, 1.f) + wv[e]);    // exp(-2(s-.5)+w)
        } else {
            if (s + MARGIN > mn)
                ns += __expf(fmaf(40.f, s, -20.f) - wv[e]);  // exp(40(s-.5)-w)
        }
    }
#pragma unroll
    for (int msk = 1; msk < 64; msk <<= 1) {
        ps += __shfl_xor(ps, msk);
        ns += __shfl_xor(ns, msk);
    }
    if (lane == 0) { sps[w] = ps; sns[w] = ns; }
    __syncthreads();
    if (t == 0) {
        ps = sps[0] + sps[1] + sps[2] + sps[3];
        ns = sns[0] + sns[1] + sns[2] + sns[3];
        rowloss[i] = log1pf(ps) * 0.5f + log1pf(ns) * 0.025f;
    }
}

__global__ void final_big(const float* __restrict__ rowloss, float* __restrict__ out) {
    __shared__ float red[256];
    int t = threadIdx.x;
    float acc = 0.f;
    for (int i = t; i < B_SZ; i += 256) acc += rowloss[i];
    red[t] = acc;
    __syncthreads();
    for (int s = 128; s > 0; s >>= 1) {
        if (t < s) red[t] += red[t + s];
        __syncthreads();
    }
    if (t == 0) out[0] = red[0] / (float)B_SZ;
}

// ================= FALLBACK PATH (round-3, proven) =================
template <int PHASE>
__global__ __launch_bounds__(256) void sim_pass(
    const unsigned short* __restrict__ fb,
    const int* __restrict__ labels,
    const float* __restrict__ simw,
    unsigned* __restrict__ minpos, unsigned* __restrict__ maxneg,
    float* __restrict__ possum, float* __restrict__ negsum) {
    __shared__ unsigned short lA[128 * 64];
    __shared__ unsigned short lB[128 * 64];
    const int t = threadIdx.x;
    const int lane = t & 63, w = t >> 6;
    const int wr = w >> 1, wc = w & 1;
    const int i0 = blockIdx.y * 128, j0 = blockIdx.x * 128;
    const int fr = lane & 15, kg = lane >> 4;
    const int srow = lane >> 3;
    const int scol = ((lane & 7) ^ srow) * 8;

    f32x4 acc[4][4];
#pragma unroll
    for (int m = 0; m < 4; ++m)
#pragma unroll
        for (int n = 0; n < 4; ++n)
            acc[m][n] = (f32x4){0.f, 0.f, 0.f, 0.f};

    const char* pA = (const char*)lA + (wr * 64 + fr) * 128;
    const char* pB = (const char*)lB + (wc * 64 + fr) * 128;
    const int q = (kg * 16) ^ ((fr & 7) << 4);

    for (int kc = 0; kc < D_SZ; kc += 64) {
        __syncthreads();
#pragma unroll
        for (int inst = 0; inst < 4; ++inst) {
            const int r8 = w * 32 + inst * 8;
            gload_lds16(fb + (size_t)(i0 + r8 + srow) * D_SZ + kc + scol, lA + r8 * 64);
            gload_lds16(fb + (size_t)(j0 + r8 + srow) * D_SZ + kc + scol, lB + r8 * 64);
        }
        asm volatile("s_waitcnt vmcnt(0)" ::: "memory");
        __syncthreads();
#pragma unroll
        for (int kk = 0; kk < 2; ++kk) {
            const int off = q ^ (kk * 64);
            bf16x8 a[4], b[4];
#pragma unroll
            for (int m = 0; m < 4; ++m)
                a[m] = *(const bf16x8*)(pA + m * 2048 + off);
#pragma unroll
            for (int n = 0; n < 4; ++n)
                b[n] = *(const bf16x8*)(pB + n * 2048 + off);
#pragma unroll
            for (int m = 0; m < 4; ++m)
#pragma unroll
                for (int n = 0; n < 4; ++n)
                    acc[m][n] = __builtin_amdgcn_mfma_f32_16x16x32_bf16(a[m], b[n], acc[m][n], 0, 0, 0);
        }
    }

    const int iBase = i0 + wr * 64, jBase = j0 + wc * 64;
    int jLab[4];
#pragma unroll
    for (int n = 0; n < 4; ++n) jLab[n] = labels[jBase + n * 16 + fr];

#pragma unroll
    for (int m = 0; m < 4; ++m) {
#pragma unroll
        for (int r = 0; r < 4; ++r) {
            const int i = iBase + m * 16 + kg * 4 + r;
            const int il = labels[i];
            if (PHASE == 0) {
                float mn = INFINITY, mx = -INFINITY;
#pragma unroll
                for (int n = 0; n < 4; ++n) {
                    float s = acc[m][n][r];
                    if (il == jLab[n]) mn = fminf(mn, s);
                    else               mx = fmaxf(mx, s);
                }
#pragma unroll
                for (int msk = 1; msk < 16; msk <<= 1) {
                    mn = fminf(mn, __shfl_xor(mn, msk));
                    mx = fmaxf(mx, __shfl_xor(mx, msk));
                }
                if (fr == 0) {
                    if (mn != INFINITY)  atomicMin(&minpos[i], fmap(mn));
                    if (mx != -INFINITY) atomicMax(&maxneg[i], fmap(mx));
                }
            } else {
                const unsigned mnu = maxneg[i];
                const float minp = funmap(minpos[i]);
                const bool hasneg = (mnu != MAXNEG_INIT);
                const float maxn = funmap(mnu);
                const float* wrow = simw + (size_t)i * B_SZ + jBase + fr;
                float ps = 0.f, ns = 0.f;
#pragma unroll
                for (int n = 0; n < 4; ++n) {
                    float s = acc[m][n][r];
                    float wv = wrow[n * 16];
                    if (il == jLab[n]) {
                        if (!hasneg || (s - MARGIN < maxn))
                            ps += __expf(fmaf(-2.f, s, 1.f) + wv);
                    } else {
                        if (s + MARGIN > minp)
                            ns += __expf(fmaf(40.f, s, -20.f) - wv);
                    }
                }
#pragma unroll
                for (int msk = 1; msk < 16; msk <<= 1) {
                    ps += __shfl_xor(ps, msk);
                    ns += __shfl_xor(ns, msk);
                }
                if (fr == 0) {
                    if (ps != 0.f) atomicAdd(&possum[i], ps);
                    if (ns != 0.f) atomicAdd(&negsum[i], ns);
                }
            }
        }
    }
}

__global__ void final_fb(const float* __restrict__ possum,
                         const float* __restrict__ negsum,
                         float* __restrict__ out) {
    __shared__ float red[256];
    int t = threadIdx.x;
    float acc = 0.f;
    for (int i = t; i < B_SZ; i += 256)
        acc += log1pf(possum[i]) * 0.5f + log1pf(negsum[i]) * 0.025f;
    red[t] = acc;
    __syncthreads();
    for (int s = 128; s > 0; s >>= 1) {
        if (t < s) red[t] += red[t + s];
        __syncthreads();
    }
    if (t == 0) out[0] = red[0] / (float)B_SZ;
}

extern "C" void kernel_launch(void* const* d_in, const int* in_sizes, int n_in,
                              void* d_out, int out_size, void* d_ws, size_t ws_size,
                              hipStream_t stream) {
    const float* feats  = (const float*)d_in[0];
    const float* simw   = (const float*)d_in[1];
    const int*   labels = (const int*)d_in[2];
    float* out = (float*)d_out;

    char* ws = (char*)d_ws;
    unsigned* minpos  = (unsigned*)ws;                       // 16 KB
    unsigned* maxneg  = (unsigned*)(ws + 1 * B_SZ * 4);      // 16 KB
    float*    possum  = (float*)(ws + 2 * B_SZ * 4);         // 16 KB
    float*    negsum  = (float*)(ws + 3 * B_SZ * 4);         // 16 KB
    float*    rowloss = (float*)(ws + 4 * B_SZ * 4);         // 16 KB
    unsigned short* fb   = (unsigned short*)(ws + 5 * B_SZ * 4);            // 2 MB
    unsigned short* simb = (unsigned short*)(ws + 5 * B_SZ * 4 + (size_t)B_SZ * D_SZ * 2); // 32 MB

    const size_t NEED_BIG = 5ull * B_SZ * 4 + (size_t)B_SZ * D_SZ * 2
                          + (size_t)B_SZ * B_SZ * 2;

    norm_init_kernel<<<B_SZ, 64, 0, stream>>>(feats, fb, minpos, maxneg, possum, negsum);

    if (ws_size >= NEED_BIG) {
        dim3 grid(B_SZ / 128, B_SZ / 128);
        gemm_store<<<grid, 256, 0, stream>>>(fb, simb);
        row_pass<<<B_SZ, 256, 0, stream>>>(simb, simw, labels, rowloss);
        final_big<<<1, 256, 0, stream>>>(rowloss, out);
    } else {
        dim3 grid(B_SZ / 128, B_SZ / 128);
        sim_pass<0><<<grid, 256, 0, stream>>>(fb, labels, simw, minpos, maxneg, possum, negsum);
        sim_pass<1><<<grid, 256, 0, stream>>>(fb, labels, simw, minpos, maxneg, possum, negsum);
        final_fb<<<1, 256, 0, stream>>>(possum, negsum, out);
    }
}

// Round 5
// 49.876 us; speedup vs baseline: 6.4710x; 1.0483x over previous
//
#include <hip/hip_runtime.h>
#include <hip/hip_bf16.h>
#include <math.h>

#define B_SZ 4096
#define D_SZ 256
#define MARGIN   0.1f

typedef __attribute__((ext_vector_type(8))) __bf16 bf16x8;
typedef __attribute__((ext_vector_type(4))) float f32x4;
typedef __attribute__((ext_vector_type(8))) unsigned short u16x8;

__device__ __forceinline__ unsigned short f2bf(float f) {
    unsigned u = __float_as_uint(f);
    unsigned r = (u + 0x7FFFu + ((u >> 16) & 1u)) >> 16;   // RNE
    return (unsigned short)r;
}

__device__ __forceinline__ void gload_lds16(const void* g, void* lds) {
    __builtin_amdgcn_global_load_lds(
        (const __attribute__((address_space(1))) void*)g,
        (__attribute__((address_space(3))) void*)lds, 16, 0, 0);
}

// one wave per row: rsqrt(sumsq), write normalized bf16 feats
__global__ void norm_init_kernel(const float* __restrict__ feats,
                                 unsigned short* __restrict__ fb) {
    int row = blockIdx.x;
    int lane = threadIdx.x;
    const float4 v = *(const float4*)(feats + (size_t)row * D_SZ + lane * 4);
    float s = v.x * v.x + v.y * v.y + v.z * v.z + v.w * v.w;
#pragma unroll
    for (int m = 32; m; m >>= 1) s += __shfl_xor(s, m);
    float rinv = 1.0f / sqrtf(s);
    short4 st;
    st.x = (short)f2bf(v.x * rinv);
    st.y = (short)f2bf(v.y * rinv);
    st.z = (short)f2bf(v.z * rinv);
    st.w = (short)f2bf(v.w * rinv);
    *(short4*)(fb + (size_t)row * D_SZ + lane * 4) = st;
}

// 128x128 tile, BK=32 double-buffered prefetch (round-4 proven).
// LDS linear dest + pre-swizzled global source chunk (rule 21);
// fragment reads apply the same XOR -> 2-way (free) aliasing.
__device__ __forceinline__ void gemm_tile(const unsigned short* __restrict__ fb,
                                          unsigned short* lA0, unsigned short* lB0,
                                          int i0, int j0, int t, f32x4 acc[4][4]) {
    const int lane = t & 63, w = t >> 6;
    const int wr = w >> 1, wc = w & 1;
    const int fr = lane & 15, kg = lane >> 4;
    const int srow = lane >> 2, schunk = lane & 3;

#pragma unroll
    for (int m = 0; m < 4; ++m)
#pragma unroll
        for (int n = 0; n < 4; ++n) acc[m][n] = (f32x4){0.f, 0.f, 0.f, 0.f};

    auto stage = [&](int buf, int kc) {
#pragma unroll
        for (int half = 0; half < 2; ++half) {
            const int R0 = w * 32 + half * 16;       // 16 rows per instruction
            const int row = R0 + srow;
            const int off = ((schunk ^ ((row >> 1) & 3)) << 3);
            gload_lds16(fb + (size_t)(i0 + row) * D_SZ + kc + off,
                        lA0 + buf * (128 * 32) + R0 * 32);
            gload_lds16(fb + (size_t)(j0 + row) * D_SZ + kc + off,
                        lB0 + buf * (128 * 32) + R0 * 32);
        }
    };

    stage(0, 0);
    asm volatile("s_waitcnt vmcnt(0)" ::: "memory");
    __syncthreads();

#pragma unroll
    for (int s = 0; s < 8; ++s) {
        const int cur = s & 1;
        if (s < 7) stage(cur ^ 1, (s + 1) * 32);     // prefetch next K-slice
        const unsigned short* A  = lA0 + cur * (128 * 32);
        const unsigned short* Bp = lB0 + cur * (128 * 32);
        bf16x8 a[4], b[4];
#pragma unroll
        for (int m = 0; m < 4; ++m) {
            const int row = wr * 64 + m * 16 + fr;
            a[m] = *(const bf16x8*)(A + row * 32 + ((kg ^ ((row >> 1) & 3)) << 3));
        }
#pragma unroll
        for (int n = 0; n < 4; ++n) {
            const int row = wc * 64 + n * 16 + fr;
            b[n] = *(const bf16x8*)(Bp + row * 32 + ((kg ^ ((row >> 1) & 3)) << 3));
        }
#pragma unroll
        for (int m = 0; m < 4; ++m)
#pragma unroll
            for (int n = 0; n < 4; ++n)
                acc[m][n] = __builtin_amdgcn_mfma_f32_16x16x32_bf16(a[m], b[n], acc[m][n], 0, 0, 0);
        if (s < 7) {
            asm volatile("s_waitcnt vmcnt(0)" ::: "memory");
            __syncthreads();
        }
    }
}

// Symmetric GEMM: only upper-triangular blocks (bj >= bi). Off-diagonal
// blocks additionally write the transposed tile via an LDS round-trip
// (XOR-swizzled: row ^ ((col&15)<<3), 8-elem groups stay contiguous).
__global__ __launch_bounds__(256, 4) void gemm_store_sym(const unsigned short* __restrict__ fb,
                                                         unsigned short* __restrict__ simb) {
    __shared__ unsigned short sm[2 * 128 * 32 * 2];   // 32 KB, reused for T
    const int t = threadIdx.x;

    int z = blockIdx.x, bi = 0;
    while (z >= 32 - bi) { z -= 32 - bi; ++bi; }
    const int bj = bi + z;
    const int i0 = bi * 128, j0 = bj * 128;

    f32x4 acc[4][4];
    gemm_tile(fb, sm, sm + 128 * 32 * 2, i0, j0, t, acc);

    const int lane = t & 63, w = t >> 6;
    const int wr = w >> 1, wc = w & 1, fr = lane & 15, kg = lane >> 4;

    // direct store (register epilogue, quarter-wave 32B-merged 2B stores)
#pragma unroll
    for (int m = 0; m < 4; ++m)
#pragma unroll
        for (int r = 0; r < 4; ++r) {
            const size_t row = i0 + wr * 64 + m * 16 + kg * 4 + r;
#pragma unroll
            for (int n = 0; n < 4; ++n)
                simb[row * B_SZ + j0 + wc * 64 + n * 16 + fr] = f2bf(acc[m][n][r]);
        }

    if (bi == bj) return;   // diagonal tile is its own transpose

    __syncthreads();        // all waves done reading gemm LDS buffers
    unsigned short* T = sm; // overlay: T[col][row^((col&15)<<3)], 128x128 bf16
#pragma unroll
    for (int m = 0; m < 4; ++m) {
        const int rowbase = wr * 64 + m * 16 + kg * 4;
#pragma unroll
        for (int n = 0; n < 4; ++n) {
            const int col = wc * 64 + n * 16 + fr;
            short4 h;
            h.x = (short)f2bf(acc[m][n][0]);
            h.y = (short)f2bf(acc[m][n][1]);
            h.z = (short)f2bf(acc[m][n][2]);
            h.w = (short)f2bf(acc[m][n][3]);
            *(short4*)(T + col * 128 + (rowbase ^ ((col & 15) << 3))) = h;
        }
    }
    __syncthreads();

    // transposed store: T row c -> simb[j0+c][i0 + r0*8 .. +7], b128 coalesced
    const int r0 = t & 15, cb = t >> 4;
#pragma unroll
    for (int p = 0; p < 8; ++p) {
        const int c = cb + p * 16;
        u16x8 v = *(const u16x8*)(T + c * 128 + 8 * (r0 ^ (c & 15)));
        *(u16x8*)(simb + (size_t)(j0 + c) * B_SZ + i0 + r0 * 8) = v;
    }
}

// one block per row: stream sim(bf16) + simw + labels, block-local min/max,
// then exp sums from the SAME registers. No atomics -> bit-deterministic.
__global__ __launch_bounds__(256) void row_pass(const unsigned short* __restrict__ simb,
                                                const float* __restrict__ simw,
                                                const int* __restrict__ labels,
                                                float* __restrict__ rowloss) {
    const int i = blockIdx.x, t = threadIdx.x;
    const int lane = t & 63, w = t >> 6;
    const int il = labels[i];
    float sv[16], wv[16];
    int lj[16];
    {
        const u16x8* sp = (const u16x8*)(simb + (size_t)i * B_SZ + t * 16);
        u16x8 s0 = sp[0], s1 = sp[1];
#pragma unroll
        for (int e = 0; e < 8; ++e) {
            sv[e]     = __uint_as_float((unsigned)s0[e] << 16);
            sv[8 + e] = __uint_as_float((unsigned)s1[e] << 16);
        }
        const float4* wp = (const float4*)(simw + (size_t)i * B_SZ + t * 16);
#pragma unroll
        for (int q = 0; q < 4; ++q) {
            float4 wq = wp[q];
            wv[q * 4 + 0] = wq.x; wv[q * 4 + 1] = wq.y;
            wv[q * 4 + 2] = wq.z; wv[q * 4 + 3] = wq.w;
        }
        const int4* lp = (const int4*)(labels + t * 16);
#pragma unroll
        for (int q = 0; q < 4; ++q) {
            int4 lq = lp[q];
            lj[q * 4 + 0] = lq.x; lj[q * 4 + 1] = lq.y;
            lj[q * 4 + 2] = lq.z; lj[q * 4 + 3] = lq.w;
        }
    }
    float mn = INFINITY, mx = -INFINITY;
#pragma unroll
    for (int e = 0; e < 16; ++e) {
        if (lj[e] == il) mn = fminf(mn, sv[e]);
        else             mx = fmaxf(mx, sv[e]);
    }
#pragma unroll
    for (int msk = 1; msk < 64; msk <<= 1) {
        mn = fminf(mn, __shfl_xor(mn, msk));
        mx = fmaxf(mx, __shfl_xor(mx, msk));
    }
    __shared__ float smn[4], smx[4], sps[4], sns[4];
    if (lane == 0) { smn[w] = mn; smx[w] = mx; }
    __syncthreads();
    mn = fminf(fminf(smn[0], smn[1]), fminf(smn[2], smn[3]));
    mx = fmaxf(fmaxf(smx[0], smx[1]), fmaxf(smx[2], smx[3]));
    const bool hasneg = (mx != -INFINITY);
    float ps = 0.f, ns = 0.f;
#pragma unroll
    for (int e = 0; e < 16; ++e) {
        const float s = sv[e];
        if (lj[e] == il) {
            if (!hasneg || (s - MARGIN < mx))
                ps += __expf(fmaf(-2.f, s, 1.f) + wv[e]);    // exp(-2(s-.5)+w)
        } else {
            if (s + MARGIN > mn)
                ns += __expf(fmaf(40.f, s, -20.f) - wv[e]);  // exp(40(s-.5)-w)
        }
    }
#pragma unroll
    for (int msk = 1; msk < 64; msk <<= 1) {
        ps += __shfl_xor(ps, msk);
        ns += __shfl_xor(ns, msk);
    }
    if (lane == 0) { sps[w] = ps; sns[w] = ns; }
    __syncthreads();
    if (t == 0) {
        ps = sps[0] + sps[1] + sps[2] + sps[3];
        ns = sns[0] + sns[1] + sns[2] + sns[3];
        rowloss[i] = log1pf(ps) * 0.5f + log1pf(ns) * 0.025f;
    }
}

__global__ void final_big(const float* __restrict__ rowloss, float* __restrict__ out) {
    __shared__ float red[256];
    int t = threadIdx.x;
    float acc = 0.f;
    for (int i = t; i < B_SZ; i += 256) acc += rowloss[i];
    red[t] = acc;
    __syncthreads();
    for (int s = 128; s > 0; s >>= 1) {
        if (t < s) red[t] += red[t + s];
        __syncthreads();
    }
    if (t == 0) out[0] = red[0] / (float)B_SZ;
}

extern "C" void kernel_launch(void* const* d_in, const int* in_sizes, int n_in,
                              void* d_out, int out_size, void* d_ws, size_t ws_size,
                              hipStream_t stream) {
    const float* feats  = (const float*)d_in[0];
    const float* simw   = (const float*)d_in[1];
    const int*   labels = (const int*)d_in[2];
    float* out = (float*)d_out;

    char* ws = (char*)d_ws;
    float*    rowloss = (float*)ws;                                  // 16 KB
    unsigned short* fb   = (unsigned short*)(ws + B_SZ * 4);         // 2 MB
    unsigned short* simb = (unsigned short*)(ws + B_SZ * 4 + (size_t)B_SZ * D_SZ * 2); // 32 MB

    norm_init_kernel<<<B_SZ, 64, 0, stream>>>(feats, fb);

    gemm_store_sym<<<528, 256, 0, stream>>>(fb, simb);
    row_pass<<<B_SZ, 256, 0, stream>>>(simb, simw, labels, rowloss);
    final_big<<<1, 256, 0, stream>>>(rowloss, out);
}